// Round 19
// baseline (212.261 us; speedup 1.0000x reference)
//
#include <hip/hip_runtime.h>

typedef __attribute__((ext_vector_type(8))) short bf16x8;
typedef __attribute__((ext_vector_type(4))) float f32x4;
typedef __attribute__((ext_vector_type(4))) unsigned u32x4;
typedef unsigned short ushortT;

#define B_   8
#define S_   1024
#define D_   512
#define DH_  256
#define NH_  4
#define DEP_ 64
#define LOG2E 1.4426950408889634f

__device__ __forceinline__ unsigned short f2bf(float f){
    unsigned u = __builtin_bit_cast(unsigned, f);
    u += 0x7fffu + ((u>>16)&1u);          // round-to-nearest-even
    return (unsigned short)(u>>16);
}
__device__ __forceinline__ float bf2f(ushortT v){
    unsigned u = ((unsigned)v)<<16;
    return __builtin_bit_cast(float, u);
}
__device__ __forceinline__ unsigned fbits(float f){ return __builtin_bit_cast(unsigned, f); }
// hot LDS tiles: 128B rows with XOR-16B swizzle -> conflict-free b128 frag reads
__device__ __forceinline__ int swz(int row,int cb){ return (row<<7) + (cb ^ ((row&7)<<4)); }
// sigma: K-row permutation so QK^T C-layout == PV A-frag layout.
__device__ __forceinline__ int sigrow(int sr){
    return 16*((sr>>5) + 2*((sr>>2)&1)) + 4*((sr>>3)&3) + (sr&3);
}
// async global->LDS, 16B/lane. LDS dest must be wave-uniform base (+lane*16).
__device__ __forceinline__ void gload_lds16(const void* g, void* l){
    __builtin_amdgcn_global_load_lds(
        (const __attribute__((address_space(1))) unsigned*)(size_t)g,
        (__attribute__((address_space(3))) unsigned*)(unsigned)(size_t)l,
        16, 0, 0);
}

// ============================================================
// mega_prep: fused {prep_x | prep_w | dist_sm | prep_wo} by blockIdx:
//   [0,4096):     x f32 -> xb bf16
//   [4096,4864):  6x W -> Wt bf16 n-major + bias concat
//   [4864,5376):  dist row-softmax -> Md (sigma'd P^T layout)
//   [5376,5632):  Wo -> Wot bf16 n-major (LDS transpose)
// ============================================================
__global__ __launch_bounds__(256) void mega_prep(
    const float* __restrict__ x, ushortT* __restrict__ xb,
    const float* __restrict__ W0, const float* __restrict__ W1, const float* __restrict__ W2,
    const float* __restrict__ W3, const float* __restrict__ W4, const float* __restrict__ W5,
    const float* __restrict__ B0, const float* __restrict__ B1, const float* __restrict__ B2,
    const float* __restrict__ B3, const float* __restrict__ B4, const float* __restrict__ B5,
    ushortT* __restrict__ Wt, float* __restrict__ bias_all,
    const float* __restrict__ dist, const float* __restrict__ mask, ushortT* __restrict__ Md,
    const float* __restrict__ Wo, ushortT* __restrict__ Wot)
{
    __shared__ ushortT pl[16][1032];
    __shared__ float tt[32][33];
    const int bid = blockIdx.x;
    if (bid < 4096){
        size_t t = (size_t)bid*256 + threadIdx.x;
        float4 v = *(const float4*)(x + t*4);
        ushort4 o; o.x=f2bf(v.x); o.y=f2bf(v.y); o.z=f2bf(v.z); o.w=f2bf(v.w);
        *(ushort4*)(xb + t*4) = o;
        return;
    }
    if (bid < 4864){
        int t = (bid-4096)*256 + threadIdx.x;
        int k = t / 384;
        int n4 = (t - k*384)*4;
#pragma unroll
        for (int j=0;j<4;++j){
            int n = n4+j; int mat = n>>8, nc = n&255;
            const float* Wp = (mat==0)?W0:(mat==1)?W1:(mat==2)?W2:(mat==3)?W3:(mat==4)?W4:W5;
            Wt[(size_t)n*512 + k] = f2bf(Wp[(size_t)k*256 + nc]);
        }
        if (t < 384){
#pragma unroll
            for (int j=0;j<4;++j){
                int n = n4+j; int mat = n>>8, nc = n&255;
                const float* Bp = (mat==0)?B0:(mat==1)?B1:(mat==2)?B2:(mat==3)?B3:(mat==4)?B4:B5;
                bias_all[n] = Bp[nc];
            }
        }
        return;
    }
    if (bid < 5376){
        // ---- dist_sm ----
        const int bx = bid - 4864;                 // 0..511 = 8b x 16qb x 4w
        const int w = bx&3, qb = (bx>>2)&15, b = bx>>6;
        const int wd = threadIdx.x>>6, lane = threadIdx.x&63;
        const float* mrow = mask + (size_t)b*S_;

        for (int rr=0; rr<4; ++rr){
            const int er = 4*wd + rr;
            const int q = qb*64 + 16*w + er;
            const float* drow = dist + ((size_t)(b*1024 + q))*S_;
            float v[16];
            float mx = -1e30f;
#pragma unroll
            for (int j=0;j<4;++j){
                const int idx = j*256 + lane*4;
                float4 d = *(const float4*)(drow + idx);
                float4 mk = *(const float4*)(mrow + idx);
                v[j*4+0] = fmaf(mk.x, -1e9f, d.x); v[j*4+1] = fmaf(mk.y, -1e9f, d.y);
                v[j*4+2] = fmaf(mk.z, -1e9f, d.z); v[j*4+3] = fmaf(mk.w, -1e9f, d.w);
#pragma unroll
                for (int i=0;i<4;++i) mx = fmaxf(mx, v[j*4+i]);
            }
            mx = fmaxf(mx, __shfl_xor(mx,1));  mx = fmaxf(mx, __shfl_xor(mx,2));
            mx = fmaxf(mx, __shfl_xor(mx,4));  mx = fmaxf(mx, __shfl_xor(mx,8));
            mx = fmaxf(mx, __shfl_xor(mx,16)); mx = fmaxf(mx, __shfl_xor(mx,32));
            float s = 0.f;
#pragma unroll
            for (int i=0;i<16;++i){ v[i] = __builtin_exp2f((v[i]-mx)*LOG2E); s += v[i]; }
            s += __shfl_xor(s,1);  s += __shfl_xor(s,2);  s += __shfl_xor(s,4);
            s += __shfl_xor(s,8);  s += __shfl_xor(s,16); s += __shfl_xor(s,32);
            const float rcp = 1.f/s;
#pragma unroll
            for (int j=0;j<4;++j){
                ushort4 o;
                o.x=f2bf(v[j*4+0]*rcp); o.y=f2bf(v[j*4+1]*rcp);
                o.z=f2bf(v[j*4+2]*rcp); o.w=f2bf(v[j*4+3]*rcp);
                *(ushort4*)(&pl[er][j*256 + lane*4]) = o;
            }
        }
        __syncthreads();

        const int t = threadIdx.x;
        const int e2 = (t>>2)&15, kt2 = t&3, g2 = t>>6;
        const int koff = 32*(kt2&1) + 4*(kt2>>1) + 8*g2;
        ushortT* slab = Md + (((size_t)(b*16+qb)*16)*4 + w)*1024;
#pragma unroll
        for (int s2=0;s2<16;++s2){
            ushort4 vv = *(const ushort4*)(&pl[e2][64*s2 + koff]);
            *(ushort4*)(slab + (size_t)s2*4096 + t*4) = vv;
        }
        return;
    }
    // ---- prep_wo ----
    {
        const int bid2 = bid - 5376;              // 0..255
        const int n0 = (bid2 & 15)*32, k0 = (bid2 >> 4)*32;
        const int ty = threadIdx.x>>5, tx = threadIdx.x&31;
#pragma unroll
        for (int i=0;i<4;++i)
            tt[ty+8*i][tx] = Wo[(size_t)(k0+ty+8*i)*512 + n0+tx];
        __syncthreads();
#pragma unroll
        for (int i=0;i<4;++i)
            Wot[(size_t)(n0+ty+8*i)*512 + k0+tx] = f2bf(tt[tx][ty+8*i]);
    }
}

// ============================================================
// QKV projection, 128x128 tile, grid (12,64). Staging via
// global_load_lds width=16 (linear LDS dest, pre-swizzled global src).
// Epilogue v2: LDS-staged destination-oriented, 8 coalesced b128
// stores/thread.
// ============================================================
__global__ __launch_bounds__(256) void qkv_mfma(
    const ushortT* __restrict__ xb, const ushortT* __restrict__ Wt,
    const float* __restrict__ bias_all,
    ushortT* __restrict__ q_d, ushortT* __restrict__ k_d, ushortT* __restrict__ vt_d,
    ushortT* __restrict__ q_a, ushortT* __restrict__ k_a, ushortT* __restrict__ vt_a)
{
    __shared__ __align__(16) char sm[32768];   // As@0 16KB, Bs@16384 16KB
    const int tid = threadIdx.x;
    const int w = tid>>6, l = tid&63, g = l>>4, e = l&15;
    const int wm = w>>1, wn = w&1;
    const int n0 = blockIdx.x*128, m0 = blockIdx.y*128;

    f32x4 acc[4][4];
#pragma unroll
    for (int i=0;i<4;++i)
#pragma unroll
        for (int j=0;j<4;++j) acc[i][j] = (f32x4){0.f,0.f,0.f,0.f};

    for (int k0=0;k0<512;k0+=64){
        __syncthreads();
#pragma unroll
        for (int i=0;i<4;++i){
            const int ch  = w*256 + i*64 + l;        // 16B-chunk id 0..1023
            const int row = ch>>3;
            const int cb  = (ch&7)*16;               // LDS byte col
            const int gc  = (cb ^ ((row&7)<<4)) >> 1;// pre-swizzled ushort col
            gload_lds16(xb + (size_t)(m0+row)*512 + k0 + gc, sm + (w*4096 + i*1024));
            gload_lds16(Wt + (size_t)(n0+row)*512 + k0 + gc, sm + 16384 + (w*4096 + i*1024));
        }
        __syncthreads();
#pragma unroll
        for (int c=0;c<2;++c){
            bf16x8 a[4];
#pragma unroll
            for (int mt=0;mt<4;++mt)
                a[mt] = *(const bf16x8*)(sm + swz(64*wm + 16*mt + e, g*16 + 64*c));
#pragma unroll
            for (int nt=0;nt<4;++nt){
                bf16x8 bfr = *(const bf16x8*)(sm + 16384 + swz(64*wn + 16*nt + e, g*16 + 64*c));
#pragma unroll
                for (int mt=0;mt<4;++mt)
                    acc[mt][nt] = __builtin_amdgcn_mfma_f32_16x16x32_bf16(a[mt], bfr, acc[mt][nt], 0,0,0);
            }
        }
    }

    // ---- epilogue v2 ----
    const int mat = n0>>8;
    const int nb  = n0 + 64*wn;
    const int h   = (nb&255)>>6;
    const int mb  = m0 + 64*wm;
    const int b   = mb>>10, s0 = mb&1023;
    ushortT* base = (mat==0)?q_d:(mat==1)?k_d:(mat==2)?vt_d:(mat==3)?q_a:(mat==4)?k_a:vt_a;
    const bool isV = (mat==2)||(mat==5);

    float bi[4];
#pragma unroll
    for (int nt=0;nt<4;++nt) bi[nt] = bias_all[nb + 16*nt + e];

    __syncthreads();                          // all waves done reading As/Bs
    char* qd = sm + w*8192;                   // wave-private 8KB quadrant
#pragma unroll
    for (int nt=0;nt<4;++nt){
#pragma unroll
        for (int mt=0;mt<4;++mt){
#pragma unroll
            for (int r=0;r<4;++r){
                const int row = 16*mt + 4*g + r;     // s-local
                const int col = 16*nt + e;           // d
                const int lr = isV ? col : row;
                const int lc = isV ? row : col;
                *(ushortT*)(qd + swz(lr, lc*2)) = f2bf(acc[mt][nt][r] + bi[nt]);
            }
        }
    }
    const int rrb = l>>3, dq = l&7;
#pragma unroll
    for (int pass=0;pass<8;++pass){
        const int rr = pass*8 + rrb;
        uint4 vv = *(const uint4*)(qd + swz(rr, dq*16));
        const size_t off = isV ? ((size_t)((b*NH_+h)*DEP_ + rr)*S_ + s0 + dq*8)
                               : ((size_t)((b*NH_+h)*S_ + s0 + rr)*DEP_ + dq*8);
        *(uint4*)(base + off) = vv;
    }
}

// ============================================================
// Flash attention v5: swapped QK^T with sigma'd K rows -> in-register
// P. dist branch: M from pre-shuffled Md (bf16, 2xb128). adj branch:
// M loaded DIRECTLY from adj f32 with sigma'd offsets (4xb128) -- no
// shuffled copy needed.
// ============================================================
__global__ __launch_bounds__(256,4) void attn_mfma(
    const ushortT* __restrict__ q_d, const ushortT* __restrict__ k_d, const ushortT* __restrict__ vt_d,
    const ushortT* __restrict__ q_a, const ushortT* __restrict__ k_a, const ushortT* __restrict__ vt_a,
    const ushortT* __restrict__ Md, const float* __restrict__ adj,
    const float* __restrict__ mask, ushortT* __restrict__ cat)
{
    __shared__ __align__(16) char sm[20480];
    // Ks@0 8KB (sigma-permuted rows); Vs@8192 8KB; Msk f32[1024]@16384
    float* Msk = (float*)(sm + 16384);

    const int tid = threadIdx.x;
    const int w = tid>>6, l = tid&63, g = l>>4, e = l&15;
    const int bz = blockIdx.y;
    const int br = bz>>5;                 // 0: dist, 1: adj
    const int bh = bz&31, b = bh>>2, h = bh&3;
    const int qb = blockIdx.x;
    const int q0 = qb*64;

    const ushortT* Qg = br ? q_a  : q_d;
    const ushortT* Kg = br ? k_a  : k_d;
    const ushortT* Vg = br ? vt_a : vt_d;

    const ushortT* Qb = Qg + ((size_t)bh*S_ + q0)*DEP_;
    const ushortT* Kb = Kg + (size_t)bh*S_*DEP_;
    const ushortT* Vb = Vg + (size_t)bh*DEP_*S_;
    const ushortT* Mbase = Md + ((size_t)((b*16+qb)*16)*4 + w)*1024 + l*16;           // dist
    const float*   Ab    = adj + (size_t)(b*S_ + q0 + 16*w + e)*S_ + 8*g;             // adj
    const float*   mkb = mask + (size_t)b*S_;

    // staging decomposition
    const int srow = tid>>3, sf = tid&7;
    const int srow2 = srow+32;
    const int krow  = sigrow(srow);       // K rows permuted by sigma
    const int krow2 = sigrow(srow2);

    // hoisted Q fragments (loop-invariant); B-operand of swapped QK^T
    bf16x8 aq0 = *(const bf16x8*)(Qb + (size_t)(16*w+e)*DEP_ + 8*g);
    bf16x8 aq1 = *(const bf16x8*)(Qb + (size_t)(16*w+e)*DEP_ + 8*g + 32);

    for (int i=tid;i<S_;i+=256) Msk[i] = mkb[i] * (-1e9f*LOG2E);

    // prologue: stage step 0's K/V + M into regs
    uint4 kreg0 = *(const uint4*)(Kb + (size_t)srow*DEP_ + 8*sf);
    uint4 kreg1 = *(const uint4*)(Kb + (size_t)srow2*DEP_ + 8*sf);
    uint4 vreg0 = *(const uint4*)(Vb + (size_t)srow*S_  + 8*sf);
    uint4 vreg1 = *(const uint4*)(Vb + (size_t)srow2*S_ + 8*sf);
    bf16x8 mc0, mc1;
    f32x4  mcf[4];
    if (br==0){
        mc0 = *(const bf16x8*)(Mbase);
        mc1 = *(const bf16x8*)(Mbase + 8);
    } else {
#pragma unroll
        for (int kt=0;kt<4;++kt)
            mcf[kt] = *(const f32x4*)(Ab + 32*(kt&1) + 4*(kt>>1));
    }

    float zl = 0.f;
    f32x4 oacc[4];
#pragma unroll
    for (int dt=0;dt<4;++dt) oacc[dt] = (f32x4){0.f,0.f,0.f,0.f};

    for (int s=0;s<16;++s){
        const int k0 = s*64;
        __syncthreads();                     // prior step's LDS reads done
        *(uint4*)(sm +        swz(krow,  sf*16)) = kreg0;
        *(uint4*)(sm +        swz(krow2, sf*16)) = kreg1;
        *(uint4*)(sm + 8192 + swz(srow,  sf*16)) = vreg0;
        *(uint4*)(sm + 8192 + swz(srow2, sf*16)) = vreg1;
        __syncthreads();

        // issue next step's K/V + M loads (drain at next barrier)
        const int kn = (s<15) ? k0+64 : 0;
        kreg0 = *(const uint4*)(Kb + (size_t)(kn+srow)*DEP_ + 8*sf);
        kreg1 = *(const uint4*)(Kb + (size_t)(kn+srow2)*DEP_ + 8*sf);
        vreg0 = *(const uint4*)(Vb + (size_t)srow*S_  + kn + 8*sf);
        vreg1 = *(const uint4*)(Vb + (size_t)srow2*S_ + kn + 8*sf);
        bf16x8 mn0, mn1;
        f32x4  mnf[4];
        if (br==0){
            const size_t mo = (size_t)((s<15)?s+1:0)*4096;
            mn0 = *(const bf16x8*)(Mbase + mo);
            mn1 = *(const bf16x8*)(Mbase + mo + 8);
        } else {
#pragma unroll
            for (int kt=0;kt<4;++kt)
                mnf[kt] = *(const f32x4*)(Ab + kn + 32*(kt&1) + 4*(kt>>1));
        }

        // ---- QK^T (swapped: A = K-frag(sigma'd), B = Q-frag -> P^T) ----
        f32x4 lg[4];
#pragma unroll
        for (int kt=0;kt<4;++kt) lg[kt] = (f32x4){0.f,0.f,0.f,0.f};
        __builtin_amdgcn_s_setprio(1);
#pragma unroll
        for (int kt=0;kt<4;++kt){
            bf16x8 bk0 = *(const bf16x8*)(sm + swz(16*kt + e, g*16));
            bf16x8 bk1 = *(const bf16x8*)(sm + swz(16*kt + e, g*16 + 64));
            lg[kt] = __builtin_amdgcn_mfma_f32_16x16x32_bf16(bk0, aq0, lg[kt], 0,0,0);
            lg[kt] = __builtin_amdgcn_mfma_f32_16x16x32_bf16(bk1, aq1, lg[kt], 0,0,0);
        }
        __builtin_amdgcn_s_setprio(0);

        // softmax + M; lane's k for (kt,r) = k0 + 32(kt&1)+4(kt>>1)+8g + r
        unsigned pw[8];
#pragma unroll
        for (int kt=0;kt<4;++kt){
            const f32x4 mskv = *(const f32x4*)(Msk + k0 + 32*(kt&1) + 4*(kt>>1) + 8*g);
            float e1[4], pm[4];
#pragma unroll
            for (int r=0;r<4;++r)
                e1[r] = __builtin_exp2f(fmaf(lg[kt][r], 0.125f*LOG2E, mskv[r]));
            zl += (e1[0]+e1[1]) + (e1[2]+e1[3]);
#pragma unroll
            for (int r=0;r<4;++r){
                const int j = 4*kt + r;
                const float mj = (br==0) ? bf2f((ushortT)(j<8 ? mc0[j] : mc1[j-8]))
                                         : mcf[kt][r];
                pm[r] = e1[r]*mj;
            }
            pw[2*kt]   = __builtin_amdgcn_perm(fbits(pm[1]), fbits(pm[0]), 0x07060302u);
            pw[2*kt+1] = __builtin_amdgcn_perm(fbits(pm[3]), fbits(pm[2]), 0x07060302u);
        }
        if (br==0){ mc0 = mn0; mc1 = mn1; }
        else {
#pragma unroll
            for (int kt=0;kt<4;++kt) mcf[kt] = mnf[kt];
        }

        // P is already the PV A-fragment: c=0 <- kt0,kt2 ; c=1 <- kt1,kt3
        const bf16x8 ap0 = __builtin_bit_cast(bf16x8, (u32x4){pw[0],pw[1],pw[4],pw[5]});
        const bf16x8 ap1 = __builtin_bit_cast(bf16x8, (u32x4){pw[2],pw[3],pw[6],pw[7]});

        // ---- PV (no rescale; plain accumulate) ----
        __builtin_amdgcn_s_setprio(1);
#pragma unroll
        for (int dt=0;dt<4;++dt){
            bf16x8 bv0 = *(const bf16x8*)(sm + 8192 + swz(16*dt + e, g*16));
            oacc[dt] = __builtin_amdgcn_mfma_f32_16x16x32_bf16(ap0, bv0, oacc[dt], 0,0,0);
        }
#pragma unroll
        for (int dt=0;dt<4;++dt){
            bf16x8 bv1 = *(const bf16x8*)(sm + 8192 + swz(16*dt + e, g*16 + 64));
            oacc[dt] = __builtin_amdgcn_mfma_f32_16x16x32_bf16(ap1, bv1, oacc[dt], 0,0,0);
        }
        __builtin_amdgcn_s_setprio(0);
    }

    // reduce z across the 4 g-lanes sharing each q, then redistribute to
    // the PV output row mapping (row q-local = 4g+r).
    zl += __shfl_xor(zl,16); zl += __shfl_xor(zl,32);
    float inv[4];
#pragma unroll
    for (int r=0;r<4;++r)
        inv[r] = 1.f / __shfl(zl, (l & 48) | (4*g + r));

    const int coff = br*DH_;
#pragma unroll
    for (int dt=0;dt<4;++dt){
#pragma unroll
        for (int r=0;r<4;++r){
            int q = q0 + 16*w + 4*g + r;
            int c = coff + h*DEP_ + 16*dt + e;
            cat[((size_t)b*S_ + q)*D_ + c] = f2bf(oacc[dt][r]*inv[r]);
        }
    }
}

// ============================================================
// Output projection v2: tile 64x64, grid (8,128) = 1024 blocks.
// ============================================================
__global__ __launch_bounds__(256) void out_mfma(
    const ushortT* __restrict__ catb, const ushortT* __restrict__ Wot,
    const float* __restrict__ bo, float* __restrict__ out)
{
    __shared__ __align__(16) char sm[16384];   // As@0 8KB, Bs@8192 8KB
    const int tid = threadIdx.x;
    const int w = tid>>6, l = tid&63, g = l>>4, e = l&15;
    const int n0 = blockIdx.x*64, m0 = blockIdx.y*64;

    f32x4 acc[4];
#pragma unroll
    for (int j=0;j<4;++j) acc[j] = (f32x4){0.f,0.f,0.f,0.f};

    for (int k0=0;k0<512;k0+=64){
        __syncthreads();
#pragma unroll
        for (int i=0;i<2;++i){
            int fi = tid + i*256;
            int row = fi>>3, f = fi&7;
            *(uint4*)(sm + swz(row, f*16))        = *(const uint4*)(catb + ((size_t)(m0+row)*512 + k0 + 8*f));
            *(uint4*)(sm + 8192 + swz(row, f*16)) = *(const uint4*)(Wot  + ((size_t)(n0+row)*512 + k0 + 8*f));
        }
        __syncthreads();
#pragma unroll
        for (int c=0;c<2;++c){
            bf16x8 a = *(const bf16x8*)(sm + swz(16*w + e, g*16 + 64*c));
#pragma unroll
            for (int nt=0;nt<4;++nt){
                bf16x8 bfr = *(const bf16x8*)(sm + 8192 + swz(16*nt + e, g*16 + 64*c));
                acc[nt] = __builtin_amdgcn_mfma_f32_16x16x32_bf16(a, bfr, acc[nt], 0,0,0);
            }
        }
    }

#pragma unroll
    for (int nt=0;nt<4;++nt){
        const int n = n0 + 16*nt + e;
        const float bi = bo[n];
#pragma unroll
        for (int r=0;r<4;++r){
            const int m = m0 + 16*w + 4*g + r;
            out[(size_t)m*512 + n] = acc[nt][r] + bi;
        }
    }
}

// ============================================================
extern "C" void kernel_launch(void* const* d_in, const int* in_sizes, int n_in,
                              void* d_out, int out_size, void* d_ws, size_t ws_size,
                              hipStream_t stream)
{
    (void)in_sizes; (void)n_in; (void)out_size; (void)ws_size;

    const float* x    = (const float*)d_in[0];
    const float* mask = (const float*)d_in[1];
    const float* adj  = (const float*)d_in[2];
    const float* dist = (const float*)d_in[3];
    const float* Wqd  = (const float*)d_in[4];  const float* bqd = (const float*)d_in[5];
    const float* Wkd  = (const float*)d_in[6];  const float* bkd = (const float*)d_in[7];
    const float* Wvd  = (const float*)d_in[8];  const float* bvd = (const float*)d_in[9];
    const float* Wqa  = (const float*)d_in[10]; const float* bqa = (const float*)d_in[11];
    const float* Wka  = (const float*)d_in[12]; const float* bka = (const float*)d_in[13];
    const float* Wva  = (const float*)d_in[14]; const float* bva = (const float*)d_in[15];
    const float* Wo   = (const float*)d_in[16]; const float* bo  = (const float*)d_in[17];
    float* out = (float*)d_out;

    // ws layout (64 MiB):
    //   [0, 8.4M):      xb (mega_prep->qkv), then catb (attn->out_mfma)
    //   [8.4M, 9.97M):  Wt+bias (mega_prep->qkv)
    //   [10.0M, 10.5M): Wot (mega_prep->out_mfma)  -- no aliasing now
    //   [25.2M, 50.3M): q_d,k_d,vt_d,q_a,k_a,vt_a (qkv->attn)
    //   [50.3M, 67.1M): Md (mega_prep->attn)
    char* W = (char*)d_ws;
    ushortT* xb   = (ushortT*)(W + 0);
    ushortT* catb = (ushortT*)(W + 0);
    ushortT* Wt   = (ushortT*)(W + 8388608);
    float*   bias = (float*)  (W + 9961472);
    ushortT* Wot  = (ushortT*)(W + 10485760);
    ushortT* q_d  = (ushortT*)(W + 25165824);
    ushortT* k_d  = (ushortT*)(W + 29360128);
    ushortT* vt_d = (ushortT*)(W + 33554432);
    ushortT* q_a  = (ushortT*)(W + 37748736);
    ushortT* k_a  = (ushortT*)(W + 41943040);
    ushortT* vt_a = (ushortT*)(W + 46137344);
    ushortT* Md   = (ushortT*)(W + 50331648);

    mega_prep<<<5632, 256, 0, stream>>>(x, xb,
        Wqd,Wkd,Wvd,Wqa,Wka,Wva, bqd,bkd,bvd,bqa,bka,bva, Wt, bias,
        dist, mask, Md, Wo, Wot);
    qkv_mfma<<<dim3(12,64), 256, 0, stream>>>(xb, Wt, bias, q_d,k_d,vt_d, q_a,k_a,vt_a);
    attn_mfma<<<dim3(16,64), 256, 0, stream>>>(q_d,k_d,vt_d, q_a,k_a,vt_a,
                                               Md, adj, mask, catb);
    out_mfma<<<dim3(8,128), 256, 0, stream>>>(catb, Wot, bo, out);
}

// Round 20
// 113.178 us; speedup vs baseline: 1.8755x; 1.8755x over previous
//
#include <hip/hip_runtime.h>

typedef __attribute__((ext_vector_type(8))) short bf16x8;
typedef __attribute__((ext_vector_type(4))) float f32x4;
typedef __attribute__((ext_vector_type(4))) unsigned u32x4;
typedef unsigned short ushortT;

#define B_   8
#define S_   1024
#define D_   512
#define DH_  256
#define NH_  4
#define DEP_ 64
#define LOG2E 1.4426950408889634f

__device__ __forceinline__ unsigned short f2bf(float f){
    unsigned u = __builtin_bit_cast(unsigned, f);
    u += 0x7fffu + ((u>>16)&1u);          // round-to-nearest-even
    return (unsigned short)(u>>16);
}
__device__ __forceinline__ float bf2f(ushortT v){
    unsigned u = ((unsigned)v)<<16;
    return __builtin_bit_cast(float, u);
}
__device__ __forceinline__ unsigned fbits(float f){ return __builtin_bit_cast(unsigned, f); }
// hot LDS tiles: 128B rows with XOR-16B swizzle -> conflict-free b128 frag reads
__device__ __forceinline__ int swz(int row,int cb){ return (row<<7) + (cb ^ ((row&7)<<4)); }
// sigma: K-row permutation so QK^T C-layout == PV A-frag layout.
__device__ __forceinline__ int sigrow(int sr){
    return 16*((sr>>5) + 2*((sr>>2)&1)) + 4*((sr>>3)&3) + (sr&3);
}
// async global->LDS, 16B/lane. LDS dest must be wave-uniform base (+lane*16).
__device__ __forceinline__ void gload_lds16(const void* g, void* l){
    __builtin_amdgcn_global_load_lds(
        (const __attribute__((address_space(1))) unsigned*)(size_t)g,
        (__attribute__((address_space(3))) unsigned*)(unsigned)(size_t)l,
        16, 0, 0);
}

// ============================================================
// mega_prep: fused {prep_x | prep_w | dist_sm} by blockIdx range.
//   [0,4096):     x f32 -> xb bf16
//   [4096,4864):  6x W -> Wt bf16 n-major + bias concat
//   [4864,5376):  dist row-softmax -> Md (sigma'd P^T layout)
// ============================================================
__global__ __launch_bounds__(256) void mega_prep(
    const float* __restrict__ x, ushortT* __restrict__ xb,
    const float* __restrict__ W0, const float* __restrict__ W1, const float* __restrict__ W2,
    const float* __restrict__ W3, const float* __restrict__ W4, const float* __restrict__ W5,
    const float* __restrict__ B0, const float* __restrict__ B1, const float* __restrict__ B2,
    const float* __restrict__ B3, const float* __restrict__ B4, const float* __restrict__ B5,
    ushortT* __restrict__ Wt, float* __restrict__ bias_all,
    const float* __restrict__ dist, const float* __restrict__ mask, ushortT* __restrict__ Md)
{
    __shared__ ushortT pl[16][1032];
    const int bid = blockIdx.x;
    if (bid < 4096){
        size_t t = (size_t)bid*256 + threadIdx.x;
        float4 v = *(const float4*)(x + t*4);
        ushort4 o; o.x=f2bf(v.x); o.y=f2bf(v.y); o.z=f2bf(v.z); o.w=f2bf(v.w);
        *(ushort4*)(xb + t*4) = o;
        return;
    }
    if (bid < 4864){
        int t = (bid-4096)*256 + threadIdx.x;
        int k = t / 384;
        int n4 = (t - k*384)*4;
#pragma unroll
        for (int j=0;j<4;++j){
            int n = n4+j; int mat = n>>8, nc = n&255;
            const float* Wp = (mat==0)?W0:(mat==1)?W1:(mat==2)?W2:(mat==3)?W3:(mat==4)?W4:W5;
            Wt[(size_t)n*512 + k] = f2bf(Wp[(size_t)k*256 + nc]);
        }
        if (t < 384){
#pragma unroll
            for (int j=0;j<4;++j){
                int n = n4+j; int mat = n>>8, nc = n&255;
                const float* Bp = (mat==0)?B0:(mat==1)?B1:(mat==2)?B2:(mat==3)?B3:(mat==4)?B4:B5;
                bias_all[n] = Bp[nc];
            }
        }
        return;
    }
    // ---- dist_sm ----
    const int bx = bid - 4864;                 // 0..511 = 8b x 16qb x 4w
    const int w = bx&3, qb = (bx>>2)&15, b = bx>>6;
    const int wd = threadIdx.x>>6, lane = threadIdx.x&63;
    const float* mrow = mask + (size_t)b*S_;

    for (int rr=0; rr<4; ++rr){
        const int er = 4*wd + rr;
        const int q = qb*64 + 16*w + er;
        const float* drow = dist + ((size_t)(b*1024 + q))*S_;
        float v[16];
        float mx = -1e30f;
#pragma unroll
        for (int j=0;j<4;++j){
            const int idx = j*256 + lane*4;
            float4 d = *(const float4*)(drow + idx);
            float4 mk = *(const float4*)(mrow + idx);
            v[j*4+0] = fmaf(mk.x, -1e9f, d.x); v[j*4+1] = fmaf(mk.y, -1e9f, d.y);
            v[j*4+2] = fmaf(mk.z, -1e9f, d.z); v[j*4+3] = fmaf(mk.w, -1e9f, d.w);
#pragma unroll
            for (int i=0;i<4;++i) mx = fmaxf(mx, v[j*4+i]);
        }
        mx = fmaxf(mx, __shfl_xor(mx,1));  mx = fmaxf(mx, __shfl_xor(mx,2));
        mx = fmaxf(mx, __shfl_xor(mx,4));  mx = fmaxf(mx, __shfl_xor(mx,8));
        mx = fmaxf(mx, __shfl_xor(mx,16)); mx = fmaxf(mx, __shfl_xor(mx,32));
        float s = 0.f;
#pragma unroll
        for (int i=0;i<16;++i){ v[i] = __builtin_exp2f((v[i]-mx)*LOG2E); s += v[i]; }
        s += __shfl_xor(s,1);  s += __shfl_xor(s,2);  s += __shfl_xor(s,4);
        s += __shfl_xor(s,8);  s += __shfl_xor(s,16); s += __shfl_xor(s,32);
        const float rcp = 1.f/s;
#pragma unroll
        for (int j=0;j<4;++j){
            ushort4 o;
            o.x=f2bf(v[j*4+0]*rcp); o.y=f2bf(v[j*4+1]*rcp);
            o.z=f2bf(v[j*4+2]*rcp); o.w=f2bf(v[j*4+3]*rcp);
            *(ushort4*)(&pl[er][j*256 + lane*4]) = o;
        }
    }
    __syncthreads();

    const int t = threadIdx.x;
    const int e2 = (t>>2)&15, kt2 = t&3, g2 = t>>6;
    const int koff = 32*(kt2&1) + 4*(kt2>>1) + 8*g2;
    ushortT* slab = Md + (((size_t)(b*16+qb)*16)*4 + w)*1024;
#pragma unroll
    for (int s2=0;s2<16;++s2){
        ushort4 vv = *(const ushort4*)(&pl[e2][64*s2 + koff]);
        *(ushort4*)(slab + (size_t)s2*4096 + t*4) = vv;
    }
}

// ============================================================
// prep: Wo[512][512] f32 -> Wot[512][512] bf16 (n-major), LDS transpose
// (launched AFTER attn; Wot region overlaps the then-dead Ma buffer)
// ============================================================
__global__ __launch_bounds__(256) void prep_wo(const float* __restrict__ Wo, ushortT* __restrict__ Wot){
    __shared__ float t[32][33];
    const int k0 = blockIdx.y*32, n0 = blockIdx.x*32;
    const int ty = threadIdx.x>>5, tx = threadIdx.x&31;
#pragma unroll
    for (int i=0;i<4;++i)
        t[ty+8*i][tx] = Wo[(size_t)(k0+ty+8*i)*512 + n0+tx];
    __syncthreads();
#pragma unroll
    for (int i=0;i<4;++i)
        Wot[(size_t)(n0+ty+8*i)*512 + k0+tx] = f2bf(t[tx][ty+8*i]);
}

// ============================================================
// shuf_adj: adj f32 [b][q][k] -> Ma bf16 in the sigma'd layout.
// ============================================================
__global__ __launch_bounds__(256) void shuf_adj(
    const float* __restrict__ adj, ushortT* __restrict__ Ma)
{
    __shared__ ushortT tl[64][72];
    const int bx = blockIdx.x;
    const int s = bx&15, qb = (bx>>4)&15, b = bx>>8;
    const int t = threadIdx.x;
    {
        const int qr = t>>2, c0 = (t&3)*16;
        const float* src = adj + ((size_t)(b*1024 + qb*64 + qr))*S_ + 64*s + c0;
#pragma unroll
        for (int i=0;i<4;++i){
            float4 d = *(const float4*)(src + 4*i);
            tl[qr][c0+4*i+0]=f2bf(d.x); tl[qr][c0+4*i+1]=f2bf(d.y);
            tl[qr][c0+4*i+2]=f2bf(d.z); tl[qr][c0+4*i+3]=f2bf(d.w);
        }
    }
    __syncthreads();
    const int w2 = t>>6, l = t&63, g = l>>4, e = l&15;
    ushortT o[16];
#pragma unroll
    for (int kt=0;kt<4;++kt)
        *(ushort4*)(&o[4*kt]) = *(const ushort4*)(&tl[16*w2 + e][32*(kt&1) + 4*(kt>>1) + 8*g]);
    ushortT* dst = Ma + ((((size_t)(b*16+qb)*16 + s)*4 + w2)*1024) + l*16;
    *(uint4*)(dst)     = *(uint4*)(&o[0]);
    *(uint4*)(dst + 8) = *(uint4*)(&o[8]);
}

// ============================================================
// QKV projection, 128x128 tile, grid (12,64). Staging via
// global_load_lds width=16 (linear LDS dest, pre-swizzled global src).
// Epilogue v2: LDS-staged destination-oriented, 8 coalesced b128
// stores/thread.
// ============================================================
__global__ __launch_bounds__(256) void qkv_mfma(
    const ushortT* __restrict__ xb, const ushortT* __restrict__ Wt,
    const float* __restrict__ bias_all,
    ushortT* __restrict__ q_d, ushortT* __restrict__ k_d, ushortT* __restrict__ vt_d,
    ushortT* __restrict__ q_a, ushortT* __restrict__ k_a, ushortT* __restrict__ vt_a)
{
    __shared__ __align__(16) char sm[32768];   // As@0 16KB, Bs@16384 16KB
    const int tid = threadIdx.x;
    const int w = tid>>6, l = tid&63, g = l>>4, e = l&15;
    const int wm = w>>1, wn = w&1;
    const int n0 = blockIdx.x*128, m0 = blockIdx.y*128;

    f32x4 acc[4][4];
#pragma unroll
    for (int i=0;i<4;++i)
#pragma unroll
        for (int j=0;j<4;++j) acc[i][j] = (f32x4){0.f,0.f,0.f,0.f};

    for (int k0=0;k0<512;k0+=64){
        __syncthreads();
#pragma unroll
        for (int i=0;i<4;++i){
            const int ch  = w*256 + i*64 + l;        // 16B-chunk id 0..1023
            const int row = ch>>3;
            const int cb  = (ch&7)*16;               // LDS byte col
            const int gc  = (cb ^ ((row&7)<<4)) >> 1;// pre-swizzled ushort col
            gload_lds16(xb + (size_t)(m0+row)*512 + k0 + gc, sm + (w*4096 + i*1024));
            gload_lds16(Wt + (size_t)(n0+row)*512 + k0 + gc, sm + 16384 + (w*4096 + i*1024));
        }
        __syncthreads();
#pragma unroll
        for (int c=0;c<2;++c){
            bf16x8 a[4];
#pragma unroll
            for (int mt=0;mt<4;++mt)
                a[mt] = *(const bf16x8*)(sm + swz(64*wm + 16*mt + e, g*16 + 64*c));
#pragma unroll
            for (int nt=0;nt<4;++nt){
                bf16x8 bfr = *(const bf16x8*)(sm + 16384 + swz(64*wn + 16*nt + e, g*16 + 64*c));
#pragma unroll
                for (int mt=0;mt<4;++mt)
                    acc[mt][nt] = __builtin_amdgcn_mfma_f32_16x16x32_bf16(a[mt], bfr, acc[mt][nt], 0,0,0);
            }
        }
    }

    // ---- epilogue v2 ----
    const int mat = n0>>8;
    const int nb  = n0 + 64*wn;
    const int h   = (nb&255)>>6;
    const int mb  = m0 + 64*wm;
    const int b   = mb>>10, s0 = mb&1023;
    ushortT* base = (mat==0)?q_d:(mat==1)?k_d:(mat==2)?vt_d:(mat==3)?q_a:(mat==4)?k_a:vt_a;
    const bool isV = (mat==2)||(mat==5);

    float bi[4];
#pragma unroll
    for (int nt=0;nt<4;++nt) bi[nt] = bias_all[nb + 16*nt + e];

    __syncthreads();                          // all waves done reading As/Bs
    char* qd = sm + w*8192;                   // wave-private 8KB quadrant
#pragma unroll
    for (int nt=0;nt<4;++nt){
#pragma unroll
        for (int mt=0;mt<4;++mt){
#pragma unroll
            for (int r=0;r<4;++r){
                const int row = 16*mt + 4*g + r;     // s-local
                const int col = 16*nt + e;           // d
                const int lr = isV ? col : row;
                const int lc = isV ? row : col;
                *(ushortT*)(qd + swz(lr, lc*2)) = f2bf(acc[mt][nt][r] + bi[nt]);
            }
        }
    }
    const int rrb = l>>3, dq = l&7;
#pragma unroll
    for (int pass=0;pass<8;++pass){
        const int rr = pass*8 + rrb;
        uint4 vv = *(const uint4*)(qd + swz(rr, dq*16));
        const size_t off = isV ? ((size_t)((b*NH_+h)*DEP_ + rr)*S_ + s0 + dq*8)
                               : ((size_t)((b*NH_+h)*S_ + s0 + rr)*DEP_ + dq*8);
        *(uint4*)(base + off) = vv;
    }
}

// ============================================================
// Flash attention v4 (R18): swapped QK^T with sigma'd K rows ->
// in-register P; M from pre-shuffled bf16 Md/Ma; no bank conflicts.
// ============================================================
__global__ __launch_bounds__(256,4) void attn_mfma(
    const ushortT* __restrict__ q_d, const ushortT* __restrict__ k_d, const ushortT* __restrict__ vt_d,
    const ushortT* __restrict__ q_a, const ushortT* __restrict__ k_a, const ushortT* __restrict__ vt_a,
    const ushortT* __restrict__ Md, const ushortT* __restrict__ Ma,
    const float* __restrict__ mask, ushortT* __restrict__ cat)
{
    __shared__ __align__(16) char sm[20480];
    // Ks@0 8KB (sigma-permuted rows); Vs@8192 8KB; Msk f32[1024]@16384
    float* Msk = (float*)(sm + 16384);

    const int tid = threadIdx.x;
    const int w = tid>>6, l = tid&63, g = l>>4, e = l&15;
    const int bz = blockIdx.y;
    const int br = bz>>5;                 // 0: dist, 1: adj
    const int bh = bz&31, b = bh>>2, h = bh&3;
    const int qb = blockIdx.x;
    const int q0 = qb*64;

    const ushortT* Qg = br ? q_a  : q_d;
    const ushortT* Kg = br ? k_a  : k_d;
    const ushortT* Vg = br ? vt_a : vt_d;

    const ushortT* Qb = Qg + ((size_t)bh*S_ + q0)*DEP_;
    const ushortT* Kb = Kg + (size_t)bh*S_*DEP_;
    const ushortT* Vb = Vg + (size_t)bh*DEP_*S_;
    const ushortT* Mbase = (br ? Ma : Md) + ((size_t)((b*16+qb)*16)*4 + w)*1024 + l*16;
    const float*   mkb = mask + (size_t)b*S_;

    // staging decomposition
    const int srow = tid>>3, sf = tid&7;
    const int srow2 = srow+32;
    const int krow  = sigrow(srow);       // K rows permuted by sigma
    const int krow2 = sigrow(srow2);

    // hoisted Q fragments (loop-invariant); B-operand of swapped QK^T
    bf16x8 aq0 = *(const bf16x8*)(Qb + (size_t)(16*w+e)*DEP_ + 8*g);
    bf16x8 aq1 = *(const bf16x8*)(Qb + (size_t)(16*w+e)*DEP_ + 8*g + 32);

    for (int i=tid;i<S_;i+=256) Msk[i] = mkb[i] * (-1e9f*LOG2E);

    // prologue: stage step 0's K/V + M into regs
    uint4 kreg0 = *(const uint4*)(Kb + (size_t)srow*DEP_ + 8*sf);
    uint4 kreg1 = *(const uint4*)(Kb + (size_t)srow2*DEP_ + 8*sf);
    uint4 vreg0 = *(const uint4*)(Vb + (size_t)srow*S_  + 8*sf);
    uint4 vreg1 = *(const uint4*)(Vb + (size_t)srow2*S_ + 8*sf);
    bf16x8 mc0 = *(const bf16x8*)(Mbase);
    bf16x8 mc1 = *(const bf16x8*)(Mbase + 8);

    float zl = 0.f;
    f32x4 oacc[4];
#pragma unroll
    for (int dt=0;dt<4;++dt) oacc[dt] = (f32x4){0.f,0.f,0.f,0.f};

    for (int s=0;s<16;++s){
        const int k0 = s*64;
        __syncthreads();                     // prior step's LDS reads done
        *(uint4*)(sm +        swz(krow,  sf*16)) = kreg0;
        *(uint4*)(sm +        swz(krow2, sf*16)) = kreg1;
        *(uint4*)(sm + 8192 + swz(srow,  sf*16)) = vreg0;
        *(uint4*)(sm + 8192 + swz(srow2, sf*16)) = vreg1;
        __syncthreads();

        // issue next step's K/V + M loads (drain at next barrier)
        const int kn = (s<15) ? k0+64 : 0;
        kreg0 = *(const uint4*)(Kb + (size_t)(kn+srow)*DEP_ + 8*sf);
        kreg1 = *(const uint4*)(Kb + (size_t)(kn+srow2)*DEP_ + 8*sf);
        vreg0 = *(const uint4*)(Vb + (size_t)srow*S_  + kn + 8*sf);
        vreg1 = *(const uint4*)(Vb + (size_t)srow2*S_ + kn + 8*sf);
        const size_t mo = (size_t)((s<15)?s+1:0)*4096;
        bf16x8 mn0 = *(const bf16x8*)(Mbase + mo);
        bf16x8 mn1 = *(const bf16x8*)(Mbase + mo + 8);

        // ---- QK^T (swapped: A = K-frag(sigma'd), B = Q-frag -> P^T) ----
        f32x4 lg[4];
#pragma unroll
        for (int kt=0;kt<4;++kt) lg[kt] = (f32x4){0.f,0.f,0.f,0.f};
        __builtin_amdgcn_s_setprio(1);
#pragma unroll
        for (int kt=0;kt<4;++kt){
            bf16x8 bk0 = *(const bf16x8*)(sm + swz(16*kt + e, g*16));
            bf16x8 bk1 = *(const bf16x8*)(sm + swz(16*kt + e, g*16 + 64));
            lg[kt] = __builtin_amdgcn_mfma_f32_16x16x32_bf16(bk0, aq0, lg[kt], 0,0,0);
            lg[kt] = __builtin_amdgcn_mfma_f32_16x16x32_bf16(bk1, aq1, lg[kt], 0,0,0);
        }
        __builtin_amdgcn_s_setprio(0);

        // softmax + M; lane's k for (kt,r) = k0 + 32(kt&1)+4(kt>>1)+8g + r
        unsigned pw[8];
#pragma unroll
        for (int kt=0;kt<4;++kt){
            const f32x4 mskv = *(const f32x4*)(Msk + k0 + 32*(kt&1) + 4*(kt>>1) + 8*g);
            float e1[4], pm[4];
#pragma unroll
            for (int r=0;r<4;++r)
                e1[r] = __builtin_exp2f(fmaf(lg[kt][r], 0.125f*LOG2E, mskv[r]));
            zl += (e1[0]+e1[1]) + (e1[2]+e1[3]);
#pragma unroll
            for (int r=0;r<4;++r){
                const int j = 4*kt + r;
                const float mj = bf2f((ushortT)(j<8 ? mc0[j] : mc1[j-8]));
                pm[r] = e1[r]*mj;
            }
            pw[2*kt]   = __builtin_amdgcn_perm(fbits(pm[1]), fbits(pm[0]), 0x07060302u);
            pw[2*kt+1] = __builtin_amdgcn_perm(fbits(pm[3]), fbits(pm[2]), 0x07060302u);
        }
        mc0 = mn0; mc1 = mn1;

        // P is already the PV A-fragment: c=0 <- kt0,kt2 ; c=1 <- kt1,kt3
        const bf16x8 ap0 = __builtin_bit_cast(bf16x8, (u32x4){pw[0],pw[1],pw[4],pw[5]});
        const bf16x8 ap1 = __builtin_bit_cast(bf16x8, (u32x4){pw[2],pw[3],pw[6],pw[7]});

        // ---- PV (no rescale; plain accumulate) ----
        __builtin_amdgcn_s_setprio(1);
#pragma unroll
        for (int dt=0;dt<4;++dt){
            bf16x8 bv0 = *(const bf16x8*)(sm + 8192 + swz(16*dt + e, g*16));
            oacc[dt] = __builtin_amdgcn_mfma_f32_16x16x32_bf16(ap0, bv0, oacc[dt], 0,0,0);
        }
#pragma unroll
        for (int dt=0;dt<4;++dt){
            bf16x8 bv1 = *(const bf16x8*)(sm + 8192 + swz(16*dt + e, g*16 + 64));
            oacc[dt] = __builtin_amdgcn_mfma_f32_16x16x32_bf16(ap1, bv1, oacc[dt], 0,0,0);
        }
        __builtin_amdgcn_s_setprio(0);
    }

    // reduce z across the 4 g-lanes sharing each q, then redistribute to
    // the PV output row mapping (row q-local = 4g+r).
    zl += __shfl_xor(zl,16); zl += __shfl_xor(zl,32);
    float inv[4];
#pragma unroll
    for (int r=0;r<4;++r)
        inv[r] = 1.f / __shfl(zl, (l & 48) | (4*g + r));

    const int coff = br*DH_;
#pragma unroll
    for (int dt=0;dt<4;++dt){
#pragma unroll
        for (int r=0;r<4;++r){
            int q = q0 + 16*w + 4*g + r;
            int c = coff + h*DEP_ + 16*dt + e;
            cat[((size_t)b*S_ + q)*D_ + c] = f2bf(oacc[dt][r]*inv[r]);
        }
    }
}

// ============================================================
// Output projection v2: tile 64x64, grid (8,128) = 1024 blocks.
// ============================================================
__global__ __launch_bounds__(256) void out_mfma(
    const ushortT* __restrict__ catb, const ushortT* __restrict__ Wot,
    const float* __restrict__ bo, float* __restrict__ out)
{
    __shared__ __align__(16) char sm[16384];   // As@0 8KB, Bs@8192 8KB
    const int tid = threadIdx.x;
    const int w = tid>>6, l = tid&63, g = l>>4, e = l&15;
    const int n0 = blockIdx.x*64, m0 = blockIdx.y*64;

    f32x4 acc[4];
#pragma unroll
    for (int j=0;j<4;++j) acc[j] = (f32x4){0.f,0.f,0.f,0.f};

    for (int k0=0;k0<512;k0+=64){
        __syncthreads();
#pragma unroll
        for (int i=0;i<2;++i){
            int fi = tid + i*256;
            int row = fi>>3, f = fi&7;
            *(uint4*)(sm + swz(row, f*16))        = *(const uint4*)(catb + ((size_t)(m0+row)*512 + k0 + 8*f));
            *(uint4*)(sm + 8192 + swz(row, f*16)) = *(const uint4*)(Wot  + ((size_t)(n0+row)*512 + k0 + 8*f));
        }
        __syncthreads();
#pragma unroll
        for (int c=0;c<2;++c){
            bf16x8 a = *(const bf16x8*)(sm + swz(16*w + e, g*16 + 64*c));
#pragma unroll
            for (int nt=0;nt<4;++nt){
                bf16x8 bfr = *(const bf16x8*)(sm + 8192 + swz(16*nt + e, g*16 + 64*c));
                acc[nt] = __builtin_amdgcn_mfma_f32_16x16x32_bf16(a, bfr, acc[nt], 0,0,0);
            }
        }
    }

#pragma unroll
    for (int nt=0;nt<4;++nt){
        const int n = n0 + 16*nt + e;
        const float bi = bo[n];
#pragma unroll
        for (int r=0;r<4;++r){
            const int m = m0 + 16*w + 4*g + r;
            out[(size_t)m*512 + n] = acc[nt][r] + bi;
        }
    }
}

// ============================================================
extern "C" void kernel_launch(void* const* d_in, const int* in_sizes, int n_in,
                              void* d_out, int out_size, void* d_ws, size_t ws_size,
                              hipStream_t stream)
{
    (void)in_sizes; (void)n_in; (void)out_size; (void)ws_size;

    const float* x    = (const float*)d_in[0];
    const float* mask = (const float*)d_in[1];
    const float* adj  = (const float*)d_in[2];
    const float* dist = (const float*)d_in[3];
    const float* Wqd  = (const float*)d_in[4];  const float* bqd = (const float*)d_in[5];
    const float* Wkd  = (const float*)d_in[6];  const float* bkd = (const float*)d_in[7];
    const float* Wvd  = (const float*)d_in[8];  const float* bvd = (const float*)d_in[9];
    const float* Wqa  = (const float*)d_in[10]; const float* bqa = (const float*)d_in[11];
    const float* Wka  = (const float*)d_in[12]; const float* bka = (const float*)d_in[13];
    const float* Wva  = (const float*)d_in[14]; const float* bva = (const float*)d_in[15];
    const float* Wo   = (const float*)d_in[16]; const float* bo  = (const float*)d_in[17];
    float* out = (float*)d_out;

    // ws layout (64 MiB), time-multiplexed (same as R18):
    //   [0, 8.4M):     xb (mega_prep->qkv), then catb (attn->out_mfma)
    //   [8.4M, 25.2M): Wt+bias (mega_prep->qkv), then Ma (shuf_adj->attn),
    //                  then Wot (prep_wo->out_mfma; prep_wo runs AFTER attn)
    //   [25.2M, 50.3M): q_d,k_d,vt_d,q_a,k_a,vt_a (qkv->attn)
    //   [50.3M, 67.1M): Md (mega_prep->attn)
    char* W = (char*)d_ws;
    ushortT* xb   = (ushortT*)(W + 0);
    ushortT* catb = (ushortT*)(W + 0);
    ushortT* Wt   = (ushortT*)(W + 8388608);
    ushortT* Ma   = (ushortT*)(W + 8388608);
    ushortT* Wot  = (ushortT*)(W + 8388608);
    float*   bias = (float*)  (W + 9961472);
    ushortT* q_d  = (ushortT*)(W + 25165824);
    ushortT* k_d  = (ushortT*)(W + 29360128);
    ushortT* vt_d = (ushortT*)(W + 33554432);
    ushortT* q_a  = (ushortT*)(W + 37748736);
    ushortT* k_a  = (ushortT*)(W + 41943040);
    ushortT* vt_a = (ushortT*)(W + 46137344);
    ushortT* Md   = (ushortT*)(W + 50331648);

    mega_prep<<<5376, 256, 0, stream>>>(x, xb,
        Wqd,Wkd,Wvd,Wqa,Wka,Wva, bqd,bkd,bvd,bqa,bka,bva, Wt, bias,
        dist, mask, Md);
    qkv_mfma<<<dim3(12,64), 256, 0, stream>>>(xb, Wt, bias, q_d,k_d,vt_d, q_a,k_a,vt_a);
    shuf_adj<<<2048, 256, 0, stream>>>(adj, Ma);
    attn_mfma<<<dim3(16,64), 256, 0, stream>>>(q_d,k_d,vt_d, q_a,k_a,vt_a,
                                               Md, Ma, mask, catb);
    prep_wo<<<dim3(16,16), 256, 0, stream>>>(Wo, Wot);
    out_mfma<<<dim3(8,128), 256, 0, stream>>>(catb, Wot, bo, out);
}